// Round 9
// baseline (203.783 us; speedup 1.0000x reference)
//
#include <hip/hip_runtime.h>

// MPOLinear3: out[B,x,y,z] = sum_{a,b,c} x[B,a,b,c]*F[a,x]*M2[b,y]*L[c,z] + bias
// where F = sum_j first[a,j,x], M2 = sum_{r1,r2} middle[b,r1,r2,y], L = sum_j last[c,j,z].
// (Reference einsums sum rank axes independently -> pure Kronecker of 3 16x16 mats.)
//
// R9: ILP attack. R8 proved occupancy (38->82%) changes nothing -> per-wave
// dependency stalls dominate and extra waves don't cover them. One block now
// does 4 rows: 4 independent chains per wave (64 up-front loads, 4x acc sets
// per weight, barriers /4). LDS 69.6KB -> 2 blocks/CU: deliberately trading
// TLP (proven useless) for ILP. Weights stay in __constant__ (R7: neutral).

#define LEG 16

typedef float f4 __attribute__((ext_vector_type(4)));

__constant__ float Wc[768];   // WF[16][16] | WM[16][16] | WL[16][16]

// Prep: reduce cores into W (d_ws): WF[x*16+a]=F[a,x], WM[y*16+b]=M2[b,y], WL[z*16+c]=L[c,z]
__global__ __launch_bounds__(256) void mpo_prep(
    const float* __restrict__ first, const float* __restrict__ middle,
    const float* __restrict__ last, float* __restrict__ W)
{
    __shared__ float red[256];
    const int t = threadIdx.x;
    const int blk = blockIdx.x;
    if (blk == 0) {
        const int xo = t >> 4, a = t & 15;
        float s = 0.f;
        #pragma unroll 8
        for (int j = 0; j < 64; ++j) s += first[a * 1024 + j * 16 + xo];
        W[t] = s;                       // WF[xo*16 + a]
    } else if (blk == 1) {
        const int z = t >> 4, c = t & 15;
        float s = 0.f;
        #pragma unroll 8
        for (int j = 0; j < 64; ++j) s += last[c * 1024 + j * 16 + z];
        W[512 + t] = s;                 // WL[z*16 + c]
    } else {
        const int b = blk - 2;          // 0..15
        const int g = t >> 4, y = t & 15;
        float s = 0.f;
        for (int r1 = g; r1 < 64; r1 += 16) {
            const float* p = middle + (size_t)b * 65536 + (size_t)r1 * 1024 + y;
            #pragma unroll 8
            for (int r2 = 0; r2 < 64; ++r2) s += p[r2 * 16];
        }
        red[t] = s;
        __syncthreads();
        if (t < 16) {
            float tot = 0.f;
            #pragma unroll
            for (int g2 = 0; g2 < 16; ++g2) tot += red[g2 * 16 + t];
            W[256 + t * 16 + b] = tot;  // WM[y*16 + b]
        }
    }
}

// Main: one block = 4 rows; 3 LDS stages, 4x-interleaved dependency chains.
__global__ __launch_bounds__(256) void mpo_main(
    const float* __restrict__ x, const float* __restrict__ bias,
    float* __restrict__ out, int nrows)
{
    __shared__ float buf[4][4352];   // per row: t1 [xo*264+bc] (4224), then t2 [p*17+c] (4352)

    const int t = threadIdx.x;
    const int row0 = blockIdx.x * 4;
    const float* WF = Wc;         // [x][a]
    const float* WM = Wc + 256;   // [y][b]
    const float* WL = Wc + 512;   // [z][c]

    // ---- Stage 1: thread owns bc=t; 64 coalesced loads (4 rows x 16 chunks)
    {
        float xa[4][16];
        #pragma unroll
        for (int r = 0; r < 4; ++r) {
            const float* xrow = x + (size_t)(row0 + r) * 4096;
            #pragma unroll
            for (int a = 0; a < 16; ++a)
                xa[r][a] = xrow[a * 256 + t];
        }
        #pragma unroll
        for (int q = 0; q < 4; ++q) {
            float acc[4][4] = {};
            #pragma unroll
            for (int a = 0; a < 16; ++a) {
                #pragma unroll
                for (int j = 0; j < 4; ++j) {
                    const float wf = WF[(q * 4 + j) * 16 + a];
                    #pragma unroll
                    for (int r = 0; r < 4; ++r)
                        acc[r][j] += xa[r][a] * wf;
                }
            }
            #pragma unroll
            for (int r = 0; r < 4; ++r)
                #pragma unroll
                for (int j = 0; j < 4; ++j)
                    buf[r][(q * 4 + j) * 264 + t] = acc[r][j];
        }
    }
    __syncthreads();

    // ---- Stage 2: thread owns (xo,c); contract b
    {
        const int x_ = t >> 4, c_ = t & 15;
        float tb[4][16];
        #pragma unroll
        for (int r = 0; r < 4; ++r)
            #pragma unroll
            for (int b = 0; b < 16; ++b)
                tb[r][b] = buf[r][x_ * 264 + b * 16 + c_];
        __syncthreads();   // all t1 reads done before t2 overwrites buf

        #pragma unroll
        for (int q = 0; q < 4; ++q) {
            float acc[4][4] = {};
            #pragma unroll
            for (int b = 0; b < 16; ++b) {
                #pragma unroll
                for (int j = 0; j < 4; ++j) {
                    const float wm = WM[(q * 4 + j) * 16 + b];
                    #pragma unroll
                    for (int r = 0; r < 4; ++r)
                        acc[r][j] += tb[r][b] * wm;
                }
            }
            #pragma unroll
            for (int r = 0; r < 4; ++r)
                #pragma unroll
                for (int j = 0; j < 4; ++j)
                    buf[r][(x_ * 16 + q * 4 + j) * 17 + c_] = acc[r][j];
        }
    }
    __syncthreads();

    // ---- Stage 3: thread owns p=(xo,y)=t; contract c; store 4 rows
    {
        float tc[4][16];
        #pragma unroll
        for (int r = 0; r < 4; ++r)
            #pragma unroll
            for (int c = 0; c < 16; ++c)
                tc[r][c] = buf[r][t * 17 + c];

        f4 bv[4];
        #pragma unroll
        for (int i = 0; i < 4; ++i)
            bv[i] = *(const f4*)(bias + t * 16 + i * 4);

        #pragma unroll
        for (int r = 0; r < 4; ++r) {
            float* orow = out + (size_t)(row0 + r) * 4096;
            #pragma unroll
            for (int q = 0; q < 4; ++q) {
                float acc[4] = {bv[q].x, bv[q].y, bv[q].z, bv[q].w};
                #pragma unroll
                for (int c = 0; c < 16; ++c) {
                    #pragma unroll
                    for (int j = 0; j < 4; ++j)
                        acc[j] += tc[r][c] * WL[(q * 4 + j) * 16 + c];
                }
                f4 o;
                o.x = acc[0]; o.y = acc[1]; o.z = acc[2]; o.w = acc[3];
                *(f4*)(orow + t * 16 + q * 4) = o;
            }
        }
    }
}

extern "C" void kernel_launch(void* const* d_in, const int* in_sizes, int n_in,
                              void* d_out, int out_size, void* d_ws, size_t ws_size,
                              hipStream_t stream) {
    const float* x      = (const float*)d_in[0];
    const float* first  = (const float*)d_in[1];
    const float* middle = (const float*)d_in[2];
    const float* last   = (const float*)d_in[3];
    const float* bias   = (const float*)d_in[4];
    float* out = (float*)d_out;
    float* W   = (float*)d_ws;          // 768 floats: WF | WM | WL

    const int Brows = in_sizes[0] / 4096;   // 16384 (divisible by 4)

    hipLaunchKernelGGL(mpo_prep, dim3(18), dim3(256), 0, stream,
                       first, middle, last, W);

    // Copy reduced weights into constant memory (D2D async: graph-capture safe)
    void* wc_ptr = nullptr;
    hipGetSymbolAddress(&wc_ptr, HIP_SYMBOL(Wc));
    hipMemcpyAsync(wc_ptr, W, 768 * sizeof(float), hipMemcpyDeviceToDevice, stream);

    hipLaunchKernelGGL(mpo_main, dim3(Brows / 4), dim3(256), 0, stream,
                       x, bias, out, Brows);
}